// Round 4
// baseline (372.528 us; speedup 1.0000x reference)
//
#include <hip/hip_runtime.h>

typedef _Float16 f16x8 __attribute__((ext_vector_type(8)));
typedef float    f32x4 __attribute__((ext_vector_type(4)));

constexpr int BATCH = 2048;
constexpr int SEQ   = 512;
constexpr int H     = 50;
constexpr int NB    = 8;     // batch per block -> 256 blocks = 1 per CU
constexpr int NT    = 512;   // 8 waves, ALL do MFMA (2 per SIMD)
constexpr int RS    = 88;    // halfs per col-row (64 used + pad) = 176 B (bank spread)
constexpr int BS    = 720;   // halfs per h-block (8*88=704 +16 pad; 1440 B, bank-decorrelated)
constexpr int PSZ   = 2 * BS;   // per-buffer halfs (h1 block + h2 block)

__device__ __forceinline__ float fexp2(float x) { return __builtin_amdgcn_exp2f(x); }
__device__ __forceinline__ float frcp(float x)  { return __builtin_amdgcn_rcpf(x); }

constexpr float K1 = 1.4426950408889634f;   // log2(e)
constexpr float K2 = 2.8853900817779268f;   // 2*log2(e)

// === r12 (resubmit after infra failure): fat waves + compact broadcast panel ===
// Diagnosis (r11 PMC): step ~1378cy of which ~500-700cy is the post-barrier
// LDS read drain: 13 waves x 5 ds_read_b128 (5KB/wave, 3x-redundant panel).
// Fix: (a) 8 waves x 2 tiles -> each wave reads the panel once for 2 A-tiles;
// (b) panel stores h1,h2 each ONCE as [8 cols][88 halfs]; lanes nn and nn+8
// read the SAME address (free LDS broadcast) -> no column duplication, and
// the h1 fragments feed BOTH the Whh0 chain (gLo) and the Wih1 chain (gHi).
// Reads/step: 65 -> 32 insts (2KB/wave). Writes: 1 half per cell (no copies).
// Dual accumulators + 4-cndmask select per tile (r9 style); x via exact f32
// fma (wx=0 on L1 lanes). K-chunks per h-block: c0=k[0,32), c1=k[32,64)
// (h slots 50..63 stay zero; A is also zero there).
// Tile map: w0..w4:{2w,2w+1}, w4 pairs {8,12}, w5:{9}, w6:{10}, w7:{11}
//   -> SIMD tile load {0,1,8,12|2,3,9|4,5,10|6,7,11} = balanced (12 half-empty).
// GATE PERM unchanged: tile m phys row w <-> jj=4m+(w>>2), gate w&3; lane
// (quad,nn): reg r = gate r of unit jj=4m+quad; col=nn&7; hiL=nn>>3 = layer.
// Schedule (1 barrier/step): iter s reads sP[s&1] = {h1(s-1), h2(s-2)},
// writes sP[(s+1)&1] = {h1(s), h2(s-1)}; edges s=0,511,512 peeled.

__global__ __launch_bounds__(NT, 2) void lstm2_cp(
    const float* __restrict__ x,
    const float* __restrict__ Wih0, const float* __restrict__ Whh0,
    const float* __restrict__ bih0, const float* __restrict__ bhh0,
    const float* __restrict__ Wih1, const float* __restrict__ Whh1,
    const float* __restrict__ bih1, const float* __restrict__ bhh1,
    const float* __restrict__ fcW,  const float* __restrict__ fcb,
    float* __restrict__ out)
{
    __shared__ __align__(16) _Float16 sP[2][PSZ];   // double-buffered compact panel (5.8 KB)
    __shared__ float sXf[SEQ * NB];                 // pre-staged x (f32), 16 KB
    __shared__ float sH2f[H * NB];                  // final h2

    const int t    = threadIdx.x;
    const int wave = t >> 6, lane = t & 63;
    const int quad = lane >> 4, nn = lane & 15;
    const int bbase = blockIdx.x * NB;

    // zero both panels (unwritten slots k in [50,64) must stay 0: A is zero
    // there too, but 0 * garbage(NaN) would poison the MFMA)
    for (int i = t; i < 2 * PSZ; i += NT) ((_Float16*)sP)[i] = (_Float16)0.f;

    // ---- pre-stage ALL x as f32 (coalesced along s) ----
    for (int i = t; i < NB * SEQ; i += NT) {
        const int b = i >> 9, s = i & (SEQ - 1);
        sXf[s * NB + b] = x[(bbase + b) * SEQ + s];
    }

    // ---- tile assignment ----
    const bool two = (wave < 5);
    const int  T0  = two ? 2 * wave : wave + 4;        // w5->9, w6->10, w7->11
    const int  T1  = (wave == 4) ? 12 : 2 * wave + 1;  // w4 pairs {8,12}

    // per-lane identity: layer = hiL, batch = col
    const int hiL = nn >> 3;
    const int col = nn & 7;

    // ---- constant A-fragments (per tile: Whh0 | Wih1 | Whh1), biases, wx ----
    f16x8 aL[2][2], aI[2][2], aH[2][2];
    f32x4 bLv[2], bHv[2];
    float wx[2][4];
    #pragma unroll
    for (int tt = 0; tt < 2; ++tt) {
        const int  m    = tt ? T1 : T0;
        const int  jr   = m * 4 + (nn >> 2);       // hidden unit of A phys row nn
        const int  gate = nn & 3;
        const bool rv   = (jr < H);
        const int  lrow = gate * H + jr;           // logical W row
        #pragma unroll
        for (int c = 0; c < 2; ++c) {
            #pragma unroll
            for (int j = 0; j < 8; ++j) {
                const int k = c * 32 + quad * 8 + j;
                const bool kv = rv && (k < 50);
                aL[tt][c][j] = kv ? (_Float16)Whh0[lrow * H + k] : (_Float16)0.f;
                aI[tt][c][j] = kv ? (_Float16)Wih1[lrow * H + k] : (_Float16)0.f;
                aH[tt][c][j] = kv ? (_Float16)Whh1[lrow * H + k] : (_Float16)0.f;
            }
        }
        const int  jq = m * 4 + quad;
        const bool bv = (jq < H);
        #pragma unroll
        for (int r = 0; r < 4; ++r) {
            bLv[tt][r] = bv ? (bih0[r * H + jq] + bhh0[r * H + jq]) : 0.f;
            bHv[tt][r] = bv ? (bih1[r * H + jq] + bhh1[r * H + jq]) : 0.f;
            wx[tt][r]  = (bv && !hiL) ? Wih0[r * H + jq] : 0.f;
        }
    }

    const int jj0 = T0 * 4 + quad;                 // per-tile hidden unit
    const int jj1 = T1 * 4 + quad;
    // read base (halfs): lanes nn and nn+8 share -> broadcast
    const int rb  = col * RS + quad * 8;
    // write slots (halfs): own layer's h-block
    const int w0  = hiL * BS + col * RS + jj0;
    const int w1  = hiL * BS + col * RS + jj1;
    float c0 = 0.f, c1 = 0.f;                      // per-tile c-state (lane's layer)

    __syncthreads();

    auto body = [&](int s, const _Float16* __restrict__ br,
                    _Float16* __restrict__ bw,
                    bool doL0, bool doL1, bool last) {
        const int   sidx = (s < SEQ) ? s : 0;      // clamp (value unused at 512)
        const float xv   = sXf[sidx * NB + col];   // broadcast read

        const f16x8 q10 = *(const f16x8*)&br[rb];            // h1 k[0,32)
        const f16x8 q11 = *(const f16x8*)&br[rb + 32];       // h1 k[32,64)
        const f16x8 q20 = *(const f16x8*)&br[rb + BS];       // h2 k[0,32)
        const f16x8 q21 = *(const f16x8*)&br[rb + BS + 32];  // h2 k[32,64)

        const bool act = hiL ? doL1 : doL0;

        #pragma unroll
        for (int tt = 0; tt < 2; ++tt) {
            if (tt == 1 && !two) break;
            // L0 chain (2-dep) and L1 chain (4-dep, reuses h1 frags)
            f32x4 gLo = bLv[tt];
            gLo = __builtin_amdgcn_mfma_f32_16x16x32_f16(aL[tt][0], q10, gLo, 0, 0, 0);
            gLo = __builtin_amdgcn_mfma_f32_16x16x32_f16(aL[tt][1], q11, gLo, 0, 0, 0);
            f32x4 gHi = bHv[tt];
            gHi = __builtin_amdgcn_mfma_f32_16x16x32_f16(aI[tt][0], q10, gHi, 0, 0, 0);
            gHi = __builtin_amdgcn_mfma_f32_16x16x32_f16(aI[tt][1], q11, gHi, 0, 0, 0);
            gHi = __builtin_amdgcn_mfma_f32_16x16x32_f16(aH[tt][0], q20, gHi, 0, 0, 0);
            gHi = __builtin_amdgcn_mfma_f32_16x16x32_f16(aH[tt][1], q21, gHi, 0, 0, 0);

            float g[4];
            #pragma unroll
            for (int r = 0; r < 4; ++r)
                g[r] = fmaf(wx[tt][r], xv, hiL ? gHi[r] : gLo[r]);

            if (act) {
                float& c = tt ? c1 : c0;
                float Ei = fexp2(-K1 * g[0]);
                float Ef = fexp2(-K1 * g[1]);
                float Eg = fexp2(-K2 * fabsf(g[2]));
                float Eo = fexp2(-K1 * g[3]);
                float it = copysignf((1.f - Eg) * frcp((1.f + Ei) * (1.f + Eg)), g[2]);
                c = frcp(1.f + Ef) * c + it;
                float Ec = fexp2(-K2 * fabsf(c));
                float h  = copysignf((1.f - Ec) * frcp((1.f + Eo) * (1.f + Ec)), c);
                const int jj = tt ? jj1 : jj0;
                if (jj < H) {
                    if (last && hiL) {
                        sH2f[jj * NB + col] = h;            // h2(511) for the FC
                    } else {
                        bw[tt ? w1 : w0] = (_Float16)h;     // single copy
                    }
                }
            }
        }
        __syncthreads();   // the ONLY barrier per step
    };

    body(0, sP[0], sP[1], true, false, false);
    #pragma unroll 1
    for (int i = 0; i < 255; ++i) {
        body(2 * i + 1, sP[1], sP[0], true, true, false);
        body(2 * i + 2, sP[0], sP[1], true, true, false);
    }
    body(511, sP[1], sP[0], true, true, false);
    body(512, sP[0], sP[1], false, true, true);

    // ---- FC epilogue: out[b] = fcW . h2_last[b] + fcb ----
    if (t < NB) {
        float sum = fcb[0];
        #pragma unroll
        for (int jx = 0; jx < H; ++jx) sum += fcW[jx] * sH2f[jx * NB + t];
        out[bbase + t] = sum;
    }
}

extern "C" void kernel_launch(void* const* d_in, const int* in_sizes, int n_in,
                              void* d_out, int out_size, void* d_ws, size_t ws_size,
                              hipStream_t stream)
{
    const float* x    = (const float*)d_in[0];
    const float* Wih0 = (const float*)d_in[1];
    const float* Whh0 = (const float*)d_in[2];
    const float* bih0 = (const float*)d_in[3];
    const float* bhh0 = (const float*)d_in[4];
    const float* Wih1 = (const float*)d_in[5];
    const float* Whh1 = (const float*)d_in[6];
    const float* bih1 = (const float*)d_in[7];
    const float* bhh1 = (const float*)d_in[8];
    const float* fcW  = (const float*)d_in[9];
    const float* fcb  = (const float*)d_in[10];

    lstm2_cp<<<BATCH / NB, NT, 0, stream>>>(
        x, Wih0, Whh0, bih0, bhh0, Wih1, Whh1, bih1, bhh1, fcW, fcb,
        (float*)d_out);
}

// Round 5
// 339.616 us; speedup vs baseline: 1.0969x; 1.0969x over previous
//
#include <hip/hip_runtime.h>

typedef _Float16 f16x8 __attribute__((ext_vector_type(8)));
typedef float    f32x4 __attribute__((ext_vector_type(4)));

constexpr int BATCH = 2048;
constexpr int SEQ   = 512;
constexpr int H     = 50;
constexpr int NB    = 8;      // batch per block -> 256 blocks = 1 per CU
constexpr int NT    = 1024;   // 16 waves: 7 L0 + 7 L1 active, 4 per SIMD
constexpr int SC    = 72;     // halfs per column (144 B = 9*16B; bank-spread stride)
constexpr int HB    = 8 * SC; // h2 block offset (halfs)
constexpr int PSZ   = 2 * HB; // per-buffer halfs (1152 = 2.25 KB)

__device__ __forceinline__ float fexp2(float x) { return __builtin_amdgcn_exp2f(x); }
__device__ __forceinline__ float frcp(float x)  { return __builtin_amdgcn_rcpf(x); }

constexpr float K1 = 1.4426950408889634f;   // log2(e)
constexpr float K2 = 2.8853900817779268f;   // 2*log2(e)

// === r13: role-split waves + 3-buffer rotation + cross-phase prefetch ===
// Convoy diagnosis (r9-r12): step time tracks TLP and per-wave serial chain,
// not aggregate LDS/MFMA/conflicts. Fix: waves 0-6 = L0, waves 8-14 = L1
// (2 of each role per SIMD). L1 runs 2 phases behind L0: during phase p,
// L0 computes h1(p) [needs h1(p-1): fresh, read post-barrier] and L1
// computes h2(p-2) [needs h1(p-2): ONE PHASE OLD -> prefetched into
// registers during phase p-1; and h2(p-3): fresh read]. So post-barrier,
// L1's first 2 MFMAs issue immediately (operands ready) while L0's reads
// drain -> pipes interleave instead of convoying.
// 3-buffer rotation: phase p writes buf[p%3], reads buf[(p-1)%3]; data
// written at p-2 stays valid through p (prefetch window).
// Panel per buffer: h1 block [8 cols][72 halfs] + h2 block at +576. Cols
// 8..15 of the MFMA B-frag duplicate cols 0..7 (broadcast, free).
// ACT OWNERSHIP (the r10/r12 lesson -- keep 1 act chain per lane): per
// wave with tiles {T0,T1}, lanes nn<8 activate T0's g, lanes nn>=8
// activate T1's g (identical cols) -> full-lane act, aggregate VALU = r9.
// Tiles: wave wv<6: {2wv,2wv+1}; wv==6: {12}; wv==7: idle (barriers only).
// Phases p=0..513: L0 active p<=511, L1 active p>=2 (h2(p-2)), last=513
// writes h2(511) to sH2f. x enters as exact f32 fma on L0 lanes.
// Numerics: identical ops/roundings as r11 lineage -> absmax 4.88e-4.

__global__ __launch_bounds__(NT, 4) void lstm2_sw(
    const float* __restrict__ x,
    const float* __restrict__ Wih0, const float* __restrict__ Whh0,
    const float* __restrict__ bih0, const float* __restrict__ bhh0,
    const float* __restrict__ Wih1, const float* __restrict__ Whh1,
    const float* __restrict__ bih1, const float* __restrict__ bhh1,
    const float* __restrict__ fcW,  const float* __restrict__ fcb,
    float* __restrict__ out)
{
    __shared__ __align__(16) _Float16 sP[3][PSZ];   // 3-buffer panel, 6.75 KB
    __shared__ float sXf[SEQ * NB];                 // pre-staged x (f32), 16 KB
    __shared__ float sH2f[H * NB];                  // final h2

    const int t    = threadIdx.x;
    const int wave = t >> 6, lane = t & 63;
    const int quad = lane >> 4, nn = lane & 15;
    const int bbase = blockIdx.x * NB;

    // zero all 3 buffers (initial h=0 state AND permanent zero pads k in [50,64))
    for (int i = t; i < 3 * PSZ; i += NT) ((_Float16*)sP)[i] = (_Float16)0.f;

    // pre-stage ALL x as f32
    for (int i = t; i < NB * SEQ; i += NT) {
        const int b = i >> 9, s = i & (SEQ - 1);
        sXf[s * NB + b] = x[(bbase + b) * SEQ + s];
    }

    const bool isL1 = (wave >= 8);
    const int  wv   = wave & 7;
    const bool wOK  = (wv < 7);
    const int  T0v  = 2 * wv;           // tile 0 (12 when wv==6)
    const int  T1v  = 2 * wv + 1;       // tile 1 (dead when wv==6)
    const bool t1v  = (wv < 6);

    const int  col  = nn & 7;           // batch
    const int  selT = nn >> 3;          // act ownership: 0 -> T0, 1 -> T1
    const int  jjS  = (selT ? T1v : T0v) * 4 + quad;  // act-owned hidden unit
    const bool vOK  = wOK && (jjS < H);

    // ---- constant A-fragments, biases, x-weights ----
    // aX over h1: L0 -> Whh0, L1 -> Wih1.  aY over h2: L1 -> Whh1.
    f16x8 aX[2][2] = {}, aY[2][2] = {};
    f32x4 bias[2] = {f32x4{0,0,0,0}, f32x4{0,0,0,0}};
    float wxS[4] = {0, 0, 0, 0};
    if (wOK) {
        const float* WX = isL1 ? Wih1 : Whh0;
        #pragma unroll
        for (int tt = 0; tt < 2; ++tt) {
            const int  m    = tt ? T1v : T0v;
            const int  jr   = m * 4 + (nn >> 2);   // hidden unit of A phys row nn
            const int  gate = nn & 3;
            const bool rv   = (jr < H);
            const int  lrow = gate * H + jr;       // logical W row
            #pragma unroll
            for (int cc = 0; cc < 2; ++cc) {
                #pragma unroll
                for (int j = 0; j < 8; ++j) {
                    const int  k  = cc * 32 + quad * 8 + j;
                    const bool kv = rv && (k < H);
                    aX[tt][cc][j] = kv ? (_Float16)WX[lrow * H + k] : (_Float16)0.f;
                    aY[tt][cc][j] = (kv && isL1) ? (_Float16)Whh1[lrow * H + k]
                                                 : (_Float16)0.f;
                }
            }
            const int  jq = m * 4 + quad;
            const bool bv = (jq < H);
            #pragma unroll
            for (int r = 0; r < 4; ++r)
                bias[tt][r] = bv ? (isL1 ? bih1[r * H + jq] + bhh1[r * H + jq]
                                         : bih0[r * H + jq] + bhh0[r * H + jq])
                                 : 0.f;
        }
        if (!isL1 && jjS < H) {
            #pragma unroll
            for (int r = 0; r < 4; ++r) wxS[r] = Wih0[r * H + jjS];
        }
    }

    const int rb    = col * SC + quad * 8;                 // frag read base (halfs)
    const int wslot = (isL1 ? HB : 0) + col * SC + jjS;    // own h write slot
    float c = 0.f;                                          // c-state of owned cell
    f16x8 pf0 = {}, pf1 = {};                               // L1's prefetched h1 frags

    __syncthreads();

    auto body = [&](int sxp, _Float16* __restrict__ bw,
                    const _Float16* __restrict__ br1,
                    bool doL0, bool doL1, bool last) {
        if (wOK) {
            if (!isL1) {
                if (doL0) {
                    const f16x8 q0 = *(const f16x8*)&br1[rb];        // h1(p-1)
                    const f16x8 q1 = *(const f16x8*)&br1[rb + 32];
                    const float xv = sXf[sxp * NB + col];
                    f32x4 g0 = bias[0];
                    g0 = __builtin_amdgcn_mfma_f32_16x16x32_f16(aX[0][0], q0, g0, 0, 0, 0);
                    g0 = __builtin_amdgcn_mfma_f32_16x16x32_f16(aX[0][1], q1, g0, 0, 0, 0);
                    f32x4 g1 = bias[1];
                    if (t1v) {
                        g1 = __builtin_amdgcn_mfma_f32_16x16x32_f16(aX[1][0], q0, g1, 0, 0, 0);
                        g1 = __builtin_amdgcn_mfma_f32_16x16x32_f16(aX[1][1], q1, g1, 0, 0, 0);
                    }
                    if (vOK) {
                        float g[4];
                        #pragma unroll
                        for (int r = 0; r < 4; ++r)
                            g[r] = fmaf(wxS[r], xv, selT ? g1[r] : g0[r]);
                        float Ei = fexp2(-K1 * g[0]);
                        float Ef = fexp2(-K1 * g[1]);
                        float Eg = fexp2(-K2 * fabsf(g[2]));
                        float Eo = fexp2(-K1 * g[3]);
                        float it = copysignf((1.f - Eg) * frcp((1.f + Ei) * (1.f + Eg)), g[2]);
                        c = frcp(1.f + Ef) * c + it;
                        float Ec = fexp2(-K2 * fabsf(c));
                        float h  = copysignf((1.f - Ec) * frcp((1.f + Eo) * (1.f + Ec)), c);
                        bw[wslot] = (_Float16)h;             // h1(p)
                    }
                }
            } else {
                if (doL1) {
                    const f16x8 q0 = *(const f16x8*)&br1[HB + rb];   // h2(p-3)
                    const f16x8 q1 = *(const f16x8*)&br1[HB + rb + 32];
                    // first 2 MFMAs use prefetched h1(p-2): ready at phase start
                    f32x4 g0 = bias[0];
                    g0 = __builtin_amdgcn_mfma_f32_16x16x32_f16(aX[0][0], pf0, g0, 0, 0, 0);
                    g0 = __builtin_amdgcn_mfma_f32_16x16x32_f16(aX[0][1], pf1, g0, 0, 0, 0);
                    g0 = __builtin_amdgcn_mfma_f32_16x16x32_f16(aY[0][0], q0, g0, 0, 0, 0);
                    g0 = __builtin_amdgcn_mfma_f32_16x16x32_f16(aY[0][1], q1, g0, 0, 0, 0);
                    f32x4 g1 = bias[1];
                    if (t1v) {
                        g1 = __builtin_amdgcn_mfma_f32_16x16x32_f16(aX[1][0], pf0, g1, 0, 0, 0);
                        g1 = __builtin_amdgcn_mfma_f32_16x16x32_f16(aX[1][1], pf1, g1, 0, 0, 0);
                        g1 = __builtin_amdgcn_mfma_f32_16x16x32_f16(aY[1][0], q0, g1, 0, 0, 0);
                        g1 = __builtin_amdgcn_mfma_f32_16x16x32_f16(aY[1][1], q1, g1, 0, 0, 0);
                    }
                    if (vOK) {
                        float g[4];
                        #pragma unroll
                        for (int r = 0; r < 4; ++r) g[r] = selT ? g1[r] : g0[r];
                        float Ei = fexp2(-K1 * g[0]);
                        float Ef = fexp2(-K1 * g[1]);
                        float Eg = fexp2(-K2 * fabsf(g[2]));
                        float Eo = fexp2(-K1 * g[3]);
                        float it = copysignf((1.f - Eg) * frcp((1.f + Ei) * (1.f + Eg)), g[2]);
                        c = frcp(1.f + Ef) * c + it;
                        float Ec = fexp2(-K2 * fabsf(c));
                        float h  = copysignf((1.f - Ec) * frcp((1.f + Eo) * (1.f + Ec)), c);
                        if (last) sH2f[jjS * NB + col] = h;  // h2(511) for the FC
                        else      bw[wslot] = (_Float16)h;   // h2(p-2)
                    }
                }
                // prefetch h1(p-1) for next phase (br1 stays valid through p+1)
                pf0 = *(const f16x8*)&br1[rb];
                pf1 = *(const f16x8*)&br1[rb + 32];
            }
        }
        __syncthreads();   // the ONLY barrier per phase
    };

    // phases p = 0..513; write buf[p%3], read buf[(p-1)%3]
    body(0, sP[0], sP[2], true, false, false);           // p=0
    body(1, sP[1], sP[0], true, false, false);           // p=1
    #pragma unroll 1
    for (int k = 0; k < 170; ++k) {
        body(3 * k + 2, sP[2], sP[1], true, true, false);
        body(3 * k + 3, sP[0], sP[2], true, true, false);
        body(3 * k + 4, sP[1], sP[0], true, true, false);
    }
    body(0, sP[2], sP[1], false, true, false);           // p=512
    body(0, sP[0], sP[2], false, true, true);            // p=513

    // ---- FC epilogue: out[b] = fcW . h2_last[b] + fcb ----
    if (t < NB) {
        float sum = fcb[0];
        #pragma unroll
        for (int jx = 0; jx < H; ++jx) sum += fcW[jx] * sH2f[jx * NB + t];
        out[bbase + t] = sum;
    }
}

extern "C" void kernel_launch(void* const* d_in, const int* in_sizes, int n_in,
                              void* d_out, int out_size, void* d_ws, size_t ws_size,
                              hipStream_t stream)
{
    const float* x    = (const float*)d_in[0];
    const float* Wih0 = (const float*)d_in[1];
    const float* Whh0 = (const float*)d_in[2];
    const float* bih0 = (const float*)d_in[3];
    const float* bhh0 = (const float*)d_in[4];
    const float* Wih1 = (const float*)d_in[5];
    const float* Whh1 = (const float*)d_in[6];
    const float* bih1 = (const float*)d_in[7];
    const float* bhh1 = (const float*)d_in[8];
    const float* fcW  = (const float*)d_in[9];
    const float* fcb  = (const float*)d_in[10];

    lstm2_sw<<<BATCH / NB, NT, 0, stream>>>(
        x, Wih0, Whh0, bih0, bhh0, Wih1, Whh1, bih1, bhh1, fcW, fcb,
        (float*)d_out);
}

// Round 6
// 325.178 us; speedup vs baseline: 1.1456x; 1.0444x over previous
//
#include <hip/hip_runtime.h>

typedef _Float16 f16x8 __attribute__((ext_vector_type(8)));
typedef float    f32x4 __attribute__((ext_vector_type(4)));

constexpr int BATCH = 2048;
constexpr int SEQ   = 512;
constexpr int H     = 50;
constexpr int NB    = 8;     // batch per block -> 256 blocks = 1 per CU
constexpr int NT    = 832;   // 13 waves, ALL MFMA-active (3.25 per SIMD)
constexpr int KQ    = 4;     // panel k-chunks of 32 (K=128)
constexpr int PSZ   = KQ * 64 * 8;   // panel halfs (2048 = 4 KB)

__device__ __forceinline__ float fexp2(float x) { return __builtin_amdgcn_exp2f(x); }
__device__ __forceinline__ float frcp(float x)  { return __builtin_amdgcn_rcpf(x); }
// B-panel frag-linear address (halfs) for value (k, n), k<128, n<16
__device__ __forceinline__ int baddr(int k, int n) {
    return (((k >> 5) * 64) + (((k >> 3) & 3) * 16) + n) * 8 + (k & 7);
}

constexpr float K1 = 1.4426950408889634f;   // log2(e)
constexpr float K2 = 2.8853900817779268f;   // 2*log2(e)

// === r14: r9 frame + critical-path cuts (no restructure) ===
// Session ledger: r9=285cy-counter baseline; r10/r11/r12/r13 structural
// variants all 294-368. Facts: latency-bound step (write->barrier->read->
// dep-MFMA->serial-trans-act->write), chain depth matters (r11), de-phasing
// attempts cost more than they recover. So: keep r9 exactly, cut the path:
//  (1) L1 chain 4-deep -> two 2-deep chains + f32x4 join (saves ~2 MFMA
//      latencies on every hi-lane's act start; +8 VALU).
//  (2) x enters as exact f32 fma (wx=0 on hi lanes): removes the hi/lo f16
//      x split, the wave-15 staging path, 2 panel rows. Slightly better
//      precision (x exact).
//  (3) NT=832: 13 waves, no idle barrier-fodder waves.
// Panel k-map: k [0,50): h1 unit j=k | k [50,64): zero | k [64,114): h2
// unit j=k-64 | k [114,128): zero. Columns 8..15 duplicate batches 0..7.
// GATE PERM (r9): tile m phys row w <-> jj = 4m+(w>>2), gate w&3; after MFMA
// lane (quad,nn) reg r = gate r of hidden jj = 4m+quad, batch nn&7 -> combine
// runs in-register in the owning lane (lanes nn<8: L0; nn>=8: L1).
// Schedule (1 barrier/step): iter s reads sB[s&1] = {h1(s-1), h2(s-2)},
// writes sB[(s+1)&1] = {h1(s), h2(s-1)}; edges s=0,511,512 peeled.

__global__ __launch_bounds__(NT, 3) void lstm2_r14(
    const float* __restrict__ x,
    const float* __restrict__ Wih0, const float* __restrict__ Whh0,
    const float* __restrict__ bih0, const float* __restrict__ bhh0,
    const float* __restrict__ Wih1, const float* __restrict__ Whh1,
    const float* __restrict__ bih1, const float* __restrict__ bhh1,
    const float* __restrict__ fcW,  const float* __restrict__ fcb,
    float* __restrict__ out)
{
    __shared__ _Float16 sB[2][PSZ];     // double-buffered panel, 8 KB
    __shared__ float    sXf[SEQ * NB];  // pre-staged x (exact f32), 16 KB
    __shared__ float    sH2f[H * NB];   // final h2

    const int t    = threadIdx.x;
    const int wave = t >> 6, lane = t & 63;
    const int quad = lane >> 4, nn = lane & 15;
    const int bbase = blockIdx.x * NB;

    // zero both panels (rows k in [50,64) and [114,128) must stay 0 forever)
    for (int i = t; i < 2 * PSZ; i += NT) ((_Float16*)sB)[i] = (_Float16)0.f;

    // ---- pre-stage ALL x as f32 (coalesced along s) ----
    for (int i = t; i < NB * SEQ; i += NT) {
        const int b = i >> 9, s = i & (SEQ - 1);
        sXf[s * NB + b] = x[(bbase + b) * SEQ + s];
    }

    // ---- constant A-fragments; wave w owns tile m = w (13 waves = 13 tiles) ----
    const int  m    = wave;
    const int  jr   = m * 4 + (nn >> 2);     // hidden unit of A phys row nn
    const int  gate = nn & 3;
    const bool rv   = (jr < H);
    const int  lrow = gate * H + jr;         // logical W row

    f16x8 a0[2];       // L0: Whh0, chunks 0..1 (k<50)
    f16x8 a1[KQ];      // L1: Wih1 (k<50) + Whh1 (k in [64,114))
    #pragma unroll
    for (int q = 0; q < 2; ++q) {
        #pragma unroll
        for (int j = 0; j < 8; ++j) {
            const int k = q * 32 + quad * 8 + j;
            a0[q][j] = (rv && k < 50) ? (_Float16)Whh0[lrow * H + k] : (_Float16)0.f;
        }
    }
    #pragma unroll
    for (int q = 0; q < KQ; ++q) {
        #pragma unroll
        for (int j = 0; j < 8; ++j) {
            const int k = q * 32 + quad * 8 + j;
            _Float16 v = (_Float16)0.f;
            if (rv) {
                if      (k < 50)              v = (_Float16)Wih1[lrow * H + k];
                else if (k >= 64 && k < 114)  v = (_Float16)Whh1[lrow * H + (k - 64)];
            }
            a1[q][j] = v;
        }
    }

    // per-lane combine identity
    const int  hiH  = nn >> 3;               // 0: L0 act, 1: L1 act
    const int  col  = nn & 7;                // batch
    const int  jj   = m * 4 + quad;          // hidden unit (valid < 50)
    const bool jv   = (jj < H);

    f32x4 b0v = {0,0,0,0}, b1v = {0,0,0,0};
    float wx[4] = {0,0,0,0};                 // exact-f32 x weights (lo lanes only)
    if (jv) {
        #pragma unroll
        for (int r = 0; r < 4; ++r) {
            b0v[r] = bih0[r * H + jj] + bhh0[r * H + jj];
            b1v[r] = bih1[r * H + jj] + bhh1[r * H + jj];
            if (!hiH) wx[r] = Wih0[r * H + jj];
        }
    }

    const int  kb   = hiH ? (64 + jj) : jj;  // this lane's h row in the panel
    const int  wH0  = baddr(kb, col);        // half slot, column copy 0
    const int  wH1  = baddr(kb, col + 8);    // half slot, column copy 1
    const bool wrOK = jv;
    float c = 0.f;                           // c0 (lo lanes) or c1 (hi lanes)

    __syncthreads();

    auto body = [&](int s, const _Float16* __restrict__ br,
                    _Float16* __restrict__ bw,
                    bool doL0, bool doL1, bool last) {
        f16x8 bq[KQ];
        #pragma unroll
        for (int q = 0; q < KQ; ++q)
            bq[q] = *(const f16x8*)&br[(q * 64 + lane) * 8];

        const float xv = sXf[(s & (SEQ - 1)) * NB + col];   // broadcast read

        // three independent 2-deep chains (crit-path cut vs r9's 4-deep g1)
        f32x4 g0 = b0v;
        g0 = __builtin_amdgcn_mfma_f32_16x16x32_f16(a0[0], bq[0], g0, 0, 0, 0);
        g0 = __builtin_amdgcn_mfma_f32_16x16x32_f16(a0[1], bq[1], g0, 0, 0, 0);
        f32x4 g1a = b1v;
        g1a = __builtin_amdgcn_mfma_f32_16x16x32_f16(a1[0], bq[0], g1a, 0, 0, 0);
        g1a = __builtin_amdgcn_mfma_f32_16x16x32_f16(a1[1], bq[1], g1a, 0, 0, 0);
        f32x4 g1b = {0, 0, 0, 0};
        g1b = __builtin_amdgcn_mfma_f32_16x16x32_f16(a1[2], bq[2], g1b, 0, 0, 0);
        g1b = __builtin_amdgcn_mfma_f32_16x16x32_f16(a1[3], bq[3], g1b, 0, 0, 0);

        float g[4];
        #pragma unroll
        for (int r = 0; r < 4; ++r) {
            const float gs = hiH ? (g1a[r] + g1b[r]) : g0[r];
            g[r] = fmaf(wx[r], xv, gs);      // wx = 0 on hi lanes
        }

        const bool act = hiH ? doL1 : doL0;
        if (act) {
            float Ei = fexp2(-K1 * g[0]);
            float Ef = fexp2(-K1 * g[1]);
            float Eg = fexp2(-K2 * fabsf(g[2]));
            float Eo = fexp2(-K1 * g[3]);
            float it = copysignf((1.f - Eg) * frcp((1.f + Ei) * (1.f + Eg)), g[2]);
            c = frcp(1.f + Ef) * c + it;
            float Ec = fexp2(-K2 * fabsf(c));
            float h  = copysignf((1.f - Ec) * frcp((1.f + Eo) * (1.f + Ec)), c);
            if (wrOK) {
                if (last && hiH) {
                    sH2f[jj * NB + col] = h;        // h2(511) for the FC
                } else {
                    _Float16 hh = (_Float16)h;
                    bw[wH0] = hh;                   // column copy 0
                    bw[wH1] = hh;                   // column copy 1
                }
            }
        }
        __syncthreads();   // the ONLY barrier per step
    };

    body(0, sB[0], sB[1], true, false, false);
    #pragma unroll 1
    for (int i = 0; i < 255; ++i) {
        body(2 * i + 1, sB[1], sB[0], true, true, false);
        body(2 * i + 2, sB[0], sB[1], true, true, false);
    }
    body(511, sB[1], sB[0], true, true, false);
    body(512, sB[0], sB[1], false, true, true);

    // ---- FC epilogue: out[b] = fcW . h2_last[b] + fcb ----
    if (t < NB) {
        float sum = fcb[0];
        #pragma unroll
        for (int jx = 0; jx < H; ++jx) sum += fcW[jx] * sH2f[jx * NB + t];
        out[bbase + t] = sum;
    }
}

extern "C" void kernel_launch(void* const* d_in, const int* in_sizes, int n_in,
                              void* d_out, int out_size, void* d_ws, size_t ws_size,
                              hipStream_t stream)
{
    const float* x    = (const float*)d_in[0];
    const float* Wih0 = (const float*)d_in[1];
    const float* Whh0 = (const float*)d_in[2];
    const float* bih0 = (const float*)d_in[3];
    const float* bhh0 = (const float*)d_in[4];
    const float* Wih1 = (const float*)d_in[5];
    const float* Whh1 = (const float*)d_in[6];
    const float* bih1 = (const float*)d_in[7];
    const float* bhh1 = (const float*)d_in[8];
    const float* fcW  = (const float*)d_in[9];
    const float* fcb  = (const float*)d_in[10];

    lstm2_r14<<<BATCH / NB, NT, 0, stream>>>(
        x, Wih0, Whh0, bih0, bhh0, Wih1, Whh1, bih1, bhh1, fcW, fcb,
        (float*)d_out);
}

// Round 8
// 323.060 us; speedup vs baseline: 1.1531x; 1.0066x over previous
//
#include <hip/hip_runtime.h>

typedef _Float16 f16x8 __attribute__((ext_vector_type(8)));
typedef float    f32x4 __attribute__((ext_vector_type(4)));

constexpr int BATCH = 2048;
constexpr int SEQ   = 512;
constexpr int H     = 50;
constexpr int NB    = 8;     // batch per block -> 256 blocks = 1 per CU
constexpr int NT    = 832;   // 13 waves, ALL MFMA-active
constexpr int KQ    = 4;     // panel k-chunks of 32 (K=128)
constexpr int PSZ   = KQ * 64 * 8;   // panel halfs (2048 = 4 KB)

__device__ __forceinline__ float fexp2(float x) { return __builtin_amdgcn_exp2f(x); }
__device__ __forceinline__ float frcp(float x)  { return __builtin_amdgcn_rcpf(x); }
// B-panel frag-linear address (halfs) for value (k, n), k<128, n<16
__device__ __forceinline__ int baddr(int k, int n) {
    return (((k >> 5) * 64) + (((k >> 3) & 3) * 16) + n) * 8 + (k & 7);
}

constexpr float K1 = 1.4426950408889634f;   // log2(e)
constexpr float K2 = 2.8853900817779268f;   // 2*log2(e)

// === r15 (resubmit after infra failure): r14 frame + gate-space prescaling ===
// Ledger: r9=285, r11=294, r12=335, r13=309, r14=288-296 counter-us. All
// structural levers falsified (LDS aggregate, conflicts, MFMA count/depth,
// wave count, de-phasing). Largest measured consumer: VALU issue (59% x
// ~1365cy = ~800cy/SIMD/step). Act packing is optimal (1 chain/lane, r10/
// r12 lesson), so cut instructions PER chain: fold the -K1 (i,f,o) and
// -K2 (g~) activation scales into A-fragments, biases and x-weights at
// setup (MFMA is linear; f16 rel error unchanged; |K2 w| <= 0.41).
// Per act: Ei/Ef/Eo = exp2(g) [saves 3 mul]; Eg = exp2(-abs(g)) via free
// input modifier [saves and+mul, costs 1 xor for the sign flip];
// Ec = exp2(-abs(K2 c)) [saves and]. Net ~-5 VALU per chain x 800 chains.
// Sign bookkeeping: g[2] = -K2*g~  ->  sign(g~) = sign(-g[2]).
// Everything else (panel k-map, gate-perm, schedule, 2-copy h-writes,
// exact-f32 x fma, 3x 2-deep MFMA chains) byte-identical to r14.

__global__ __launch_bounds__(NT, 3) void lstm2_r15(
    const float* __restrict__ x,
    const float* __restrict__ Wih0, const float* __restrict__ Whh0,
    const float* __restrict__ bih0, const float* __restrict__ bhh0,
    const float* __restrict__ Wih1, const float* __restrict__ Whh1,
    const float* __restrict__ bih1, const float* __restrict__ bhh1,
    const float* __restrict__ fcW,  const float* __restrict__ fcb,
    float* __restrict__ out)
{
    __shared__ _Float16 sB[2][PSZ];     // double-buffered panel, 8 KB
    __shared__ float    sXf[SEQ * NB];  // pre-staged x (exact f32), 16 KB
    __shared__ float    sH2f[H * NB];   // final h2

    const int t    = threadIdx.x;
    const int wave = t >> 6, lane = t & 63;
    const int quad = lane >> 4, nn = lane & 15;
    const int bbase = blockIdx.x * NB;

    // zero both panels (rows k in [50,64) and [114,128) must stay 0 forever)
    for (int i = t; i < 2 * PSZ; i += NT) ((_Float16*)sB)[i] = (_Float16)0.f;

    // ---- pre-stage ALL x as f32 (coalesced along s) ----
    for (int i = t; i < NB * SEQ; i += NT) {
        const int b = i >> 9, s = i & (SEQ - 1);
        sXf[s * NB + b] = x[(bbase + b) * SEQ + s];
    }

    // ---- constant A-fragments (PRESCALED); wave w owns tile m = w ----
    const int  m    = wave;
    const int  jr   = m * 4 + (nn >> 2);     // hidden unit of A phys row nn
    const int  gate = nn & 3;                // gate of A phys row nn
    const bool rv   = (jr < H);
    const int  lrow = gate * H + jr;         // logical W row
    const float rsc = (gate == 2) ? -K2 : -K1;   // row prescale

    f16x8 a0[2];       // L0: -s*Whh0, chunks 0..1 (k<50)
    f16x8 a1[KQ];      // L1: -s*Wih1 (k<50) + -s*Whh1 (k in [64,114))
    #pragma unroll
    for (int q = 0; q < 2; ++q) {
        #pragma unroll
        for (int j = 0; j < 8; ++j) {
            const int k = q * 32 + quad * 8 + j;
            a0[q][j] = (rv && k < 50) ? (_Float16)(rsc * Whh0[lrow * H + k])
                                      : (_Float16)0.f;
        }
    }
    #pragma unroll
    for (int q = 0; q < KQ; ++q) {
        #pragma unroll
        for (int j = 0; j < 8; ++j) {
            const int k = q * 32 + quad * 8 + j;
            _Float16 v = (_Float16)0.f;
            if (rv) {
                if      (k < 50)              v = (_Float16)(rsc * Wih1[lrow * H + k]);
                else if (k >= 64 && k < 114)  v = (_Float16)(rsc * Whh1[lrow * H + (k - 64)]);
            }
            a1[q][j] = v;
        }
    }

    // per-lane combine identity
    const int  hiH  = nn >> 3;               // 0: L0 act, 1: L1 act
    const int  col  = nn & 7;                // batch
    const int  jj   = m * 4 + quad;          // hidden unit (valid < 50)
    const bool jv   = (jj < H);

    f32x4 b0v = {0,0,0,0}, b1v = {0,0,0,0};
    float wx[4] = {0,0,0,0};                 // prescaled x weights (lo lanes only)
    if (jv) {
        #pragma unroll
        for (int r = 0; r < 4; ++r) {
            const float s = (r == 2) ? -K2 : -K1;   // reg r = gate r
            b0v[r] = s * (bih0[r * H + jj] + bhh0[r * H + jj]);
            b1v[r] = s * (bih1[r * H + jj] + bhh1[r * H + jj]);
            if (!hiH) wx[r] = s * Wih0[r * H + jj];
        }
    }

    const int  kb   = hiH ? (64 + jj) : jj;  // this lane's h row in the panel
    const int  wH0  = baddr(kb, col);        // half slot, column copy 0
    const int  wH1  = baddr(kb, col + 8);    // half slot, column copy 1
    const bool wrOK = jv;
    float c = 0.f;                           // c0 (lo lanes) or c1 (hi lanes)

    __syncthreads();

    auto body = [&](int s, const _Float16* __restrict__ br,
                    _Float16* __restrict__ bw,
                    bool doL0, bool doL1, bool last) {
        f16x8 bq[KQ];
        #pragma unroll
        for (int q = 0; q < KQ; ++q)
            bq[q] = *(const f16x8*)&br[(q * 64 + lane) * 8];

        const float xv = sXf[(s & (SEQ - 1)) * NB + col];   // broadcast read

        // three independent 2-deep chains
        f32x4 g0 = b0v;
        g0 = __builtin_amdgcn_mfma_f32_16x16x32_f16(a0[0], bq[0], g0, 0, 0, 0);
        g0 = __builtin_amdgcn_mfma_f32_16x16x32_f16(a0[1], bq[1], g0, 0, 0, 0);
        f32x4 g1a = b1v;
        g1a = __builtin_amdgcn_mfma_f32_16x16x32_f16(a1[0], bq[0], g1a, 0, 0, 0);
        g1a = __builtin_amdgcn_mfma_f32_16x16x32_f16(a1[1], bq[1], g1a, 0, 0, 0);
        f32x4 g1b = {0, 0, 0, 0};
        g1b = __builtin_amdgcn_mfma_f32_16x16x32_f16(a1[2], bq[2], g1b, 0, 0, 0);
        g1b = __builtin_amdgcn_mfma_f32_16x16x32_f16(a1[3], bq[3], g1b, 0, 0, 0);

        float g[4];
        #pragma unroll
        for (int r = 0; r < 4; ++r) {
            const float gs = hiH ? (g1a[r] + g1b[r]) : g0[r];
            g[r] = fmaf(wx[r], xv, gs);      // wx = 0 on hi lanes
        }

        // g[0]=-i, g[1]=-f, g[3]=-o (nats->log2 folded); g[2]=-2*g~ (log2)
        const bool act = hiH ? doL1 : doL0;
        if (act) {
            float Ei = fexp2(g[0]);                  // e^{-i}
            float Ef = fexp2(g[1]);                  // e^{-f}
            float Eg = fexp2(-fabsf(g[2]));          // e^{-2|g~|} (free -abs mod)
            float Eo = fexp2(g[3]);                  // e^{-o}
            float it = copysignf((1.f - Eg) * frcp((1.f + Ei) * (1.f + Eg)), -g[2]);
            c = fmaf(frcp(1.f + Ef), c, it);
            float Ec = fexp2(-fabsf(K2 * c));        // e^{-2|c|}
            float h  = copysignf((1.f - Ec) * frcp((1.f + Eo) * (1.f + Ec)), c);
            if (wrOK) {
                if (last && hiH) {
                    sH2f[jj * NB + col] = h;        // h2(511) for the FC
                } else {
                    _Float16 hh = (_Float16)h;
                    bw[wH0] = hh;                   // column copy 0
                    bw[wH1] = hh;                   // column copy 1
                }
            }
        }
        __syncthreads();   // the ONLY barrier per step
    };

    body(0, sB[0], sB[1], true, false, false);
    #pragma unroll 1
    for (int i = 0; i < 255; ++i) {
        body(2 * i + 1, sB[1], sB[0], true, true, false);
        body(2 * i + 2, sB[0], sB[1], true, true, false);
    }
    body(511, sB[1], sB[0], true, true, false);
    body(512, sB[0], sB[1], false, true, true);

    // ---- FC epilogue: out[b] = fcW . h2_last[b] + fcb ----
    if (t < NB) {
        float sum = fcb[0];
        #pragma unroll
        for (int jx = 0; jx < H; ++jx) sum += fcW[jx] * sH2f[jx * NB + t];
        out[bbase + t] = sum;
    }
}

extern "C" void kernel_launch(void* const* d_in, const int* in_sizes, int n_in,
                              void* d_out, int out_size, void* d_ws, size_t ws_size,
                              hipStream_t stream)
{
    const float* x    = (const float*)d_in[0];
    const float* Wih0 = (const float*)d_in[1];
    const float* Whh0 = (const float*)d_in[2];
    const float* bih0 = (const float*)d_in[3];
    const float* bhh0 = (const float*)d_in[4];
    const float* Wih1 = (const float*)d_in[5];
    const float* Whh1 = (const float*)d_in[6];
    const float* bih1 = (const float*)d_in[7];
    const float* bhh1 = (const float*)d_in[8];
    const float* fcW  = (const float*)d_in[9];
    const float* fcb  = (const float*)d_in[10];

    lstm2_r15<<<BATCH / NB, NT, 0, stream>>>(
        x, Wih0, Whh0, bih0, bhh0, Wih1, Whh1, bih1, bhh1, fcW, fcb,
        (float*)d_out);
}

// Round 9
// 315.284 us; speedup vs baseline: 1.1816x; 1.0247x over previous
//
#include <hip/hip_runtime.h>

typedef _Float16 f16x8 __attribute__((ext_vector_type(8)));
typedef float    f32x4 __attribute__((ext_vector_type(4)));

constexpr int BATCH = 2048;
constexpr int SEQ   = 512;
constexpr int H     = 50;
constexpr int NB    = 8;     // batch per block -> 256 blocks = 1 per CU
constexpr int NT    = 832;   // 13 waves, ALL MFMA-active
constexpr int KQ    = 4;     // panel k-chunks of 32 (K=128)
constexpr int PSZ   = 1024;  // compact panel halfs per buffer (2 KB)

__device__ __forceinline__ float fexp2(float x) { return __builtin_amdgcn_exp2f(x); }
__device__ __forceinline__ float frcp(float x)  { return __builtin_amdgcn_rcpf(x); }
// compact B-panel address (halfs) for value (k, c), k<128, c<8 (single copy)
__device__ __forceinline__ int caddr(int k, int c) {
    return ((k >> 3) * 64) + c * 8 + (k & 7);
}

constexpr float K1 = 1.4426950408889634f;   // log2(e)
constexpr float K2 = 2.8853900817779268f;   // 2*log2(e)

// === r16: r15 frame + single-copy broadcast panel (LDS-drain cut at const TLP) ===
// Ledger: r9=285 r11=294 r12=335 r13=309 r14=~291 r15=~294 counter-us.
// Falsified: LDS aggregate(r12), conflicts(r11), MFMA count(r11)/depth(r14),
// wave count(r14), de-phasing(r10/r13), VALU issue(r15: -5 VALU/chain ->
// VALUBusy 59->56, time flat). Remaining suspect: post-barrier LDS SERVICE
// DRAIN as latency -- 13 waves x 4 ds_read_b128 of a 2x-duplicated panel hit
// one 128B/cy pipe; the barrier serializes on the slowest wave. Evidence:
// r9(52 reads)=1334cy vs r11(65)=1375cy -> ~3cy marginal queue delay/read.
// All waves read IDENTICAL fragments (B shared, only A per-wave), and cols
// 8..15 duplicate 0..7 -> store ONE copy; lanes nn and nn+8 read the SAME
// address (LDS same-address broadcast is free) -> each b128 serves 512B
// unique instead of 1024B. Reads stay 4/wave; h-writes 2 -> 1 per cell.
// Layout: caddr(k,c) = (k>>3)*64 + c*8 + (k&7); chunk q base = q*256 +
// quad*64 + col*8 (contiguous 512B footprint per read). Panel 2KB/buffer.
// k-map: k[0,50)=h1 unit k | k[50,64)=0 | k[64,114)=h2 unit k-64 | rest 0.
// Everything else byte-identical to r15 (prescaled gates: g=-K1/-K2-scaled
// at setup; Ei/Ef/Eo=exp2(g), Eg=exp2(-|g|), Ec=exp2(-|K2 c|)).

__global__ __launch_bounds__(NT, 3) void lstm2_r16(
    const float* __restrict__ x,
    const float* __restrict__ Wih0, const float* __restrict__ Whh0,
    const float* __restrict__ bih0, const float* __restrict__ bhh0,
    const float* __restrict__ Wih1, const float* __restrict__ Whh1,
    const float* __restrict__ bih1, const float* __restrict__ bhh1,
    const float* __restrict__ fcW,  const float* __restrict__ fcb,
    float* __restrict__ out)
{
    __shared__ _Float16 sB[2][PSZ];     // double-buffered compact panel, 4 KB
    __shared__ float    sXf[SEQ * NB];  // pre-staged x (exact f32), 16 KB
    __shared__ float    sH2f[H * NB];   // final h2

    const int t    = threadIdx.x;
    const int wave = t >> 6, lane = t & 63;
    const int quad = lane >> 4, nn = lane & 15;
    const int bbase = blockIdx.x * NB;

    // zero both panels (rows k in [50,64) and [114,128) must stay 0 forever)
    for (int i = t; i < 2 * PSZ; i += NT) ((_Float16*)sB)[i] = (_Float16)0.f;

    // ---- pre-stage ALL x as f32 (coalesced along s) ----
    for (int i = t; i < NB * SEQ; i += NT) {
        const int b = i >> 9, s = i & (SEQ - 1);
        sXf[s * NB + b] = x[(bbase + b) * SEQ + s];
    }

    // ---- constant A-fragments (PRESCALED); wave w owns tile m = w ----
    const int  m    = wave;
    const int  jr   = m * 4 + (nn >> 2);     // hidden unit of A phys row nn
    const int  gate = nn & 3;                // gate of A phys row nn
    const bool rv   = (jr < H);
    const int  lrow = gate * H + jr;         // logical W row
    const float rsc = (gate == 2) ? -K2 : -K1;   // row prescale

    f16x8 a0[2];       // L0: -s*Whh0, chunks 0..1 (k<50)
    f16x8 a1[KQ];      // L1: -s*Wih1 (k<50) + -s*Whh1 (k in [64,114))
    #pragma unroll
    for (int q = 0; q < 2; ++q) {
        #pragma unroll
        for (int j = 0; j < 8; ++j) {
            const int k = q * 32 + quad * 8 + j;
            a0[q][j] = (rv && k < 50) ? (_Float16)(rsc * Whh0[lrow * H + k])
                                      : (_Float16)0.f;
        }
    }
    #pragma unroll
    for (int q = 0; q < KQ; ++q) {
        #pragma unroll
        for (int j = 0; j < 8; ++j) {
            const int k = q * 32 + quad * 8 + j;
            _Float16 v = (_Float16)0.f;
            if (rv) {
                if      (k < 50)              v = (_Float16)(rsc * Wih1[lrow * H + k]);
                else if (k >= 64 && k < 114)  v = (_Float16)(rsc * Whh1[lrow * H + (k - 64)]);
            }
            a1[q][j] = v;
        }
    }

    // per-lane combine identity
    const int  hiH  = nn >> 3;               // 0: L0 act, 1: L1 act
    const int  col  = nn & 7;                // batch
    const int  jj   = m * 4 + quad;          // hidden unit (valid < 50)
    const bool jv   = (jj < H);

    f32x4 b0v = {0,0,0,0}, b1v = {0,0,0,0};
    float wx[4] = {0,0,0,0};                 // prescaled x weights (lo lanes only)
    if (jv) {
        #pragma unroll
        for (int r = 0; r < 4; ++r) {
            const float s = (r == 2) ? -K2 : -K1;   // reg r = gate r
            b0v[r] = s * (bih0[r * H + jj] + bhh0[r * H + jj]);
            b1v[r] = s * (bih1[r * H + jj] + bhh1[r * H + jj]);
            if (!hiH) wx[r] = s * Wih0[r * H + jj];
        }
    }

    // read bases: lanes nn and nn+8 share the address -> free broadcast
    const int rb0 = 0 * 256 + quad * 64 + col * 8;
    const int rb1 = 1 * 256 + quad * 64 + col * 8;
    const int rb2 = 2 * 256 + quad * 64 + col * 8;
    const int rb3 = 3 * 256 + quad * 64 + col * 8;
    // single write slot: k = hiH*64 + jj
    const int  wH   = caddr(hiH * 64 + jj, col);
    const bool wrOK = jv;
    float c = 0.f;                           // c0 (lo lanes) or c1 (hi lanes)

    __syncthreads();

    auto body = [&](int s, const _Float16* __restrict__ br,
                    _Float16* __restrict__ bw,
                    bool doL0, bool doL1, bool last) {
        const f16x8 bq0 = *(const f16x8*)&br[rb0];
        const f16x8 bq1 = *(const f16x8*)&br[rb1];
        const f16x8 bq2 = *(const f16x8*)&br[rb2];
        const f16x8 bq3 = *(const f16x8*)&br[rb3];

        const float xv = sXf[(s & (SEQ - 1)) * NB + col];   // broadcast read

        // three independent 2-deep chains
        f32x4 g0 = b0v;
        g0 = __builtin_amdgcn_mfma_f32_16x16x32_f16(a0[0], bq0, g0, 0, 0, 0);
        g0 = __builtin_amdgcn_mfma_f32_16x16x32_f16(a0[1], bq1, g0, 0, 0, 0);
        f32x4 g1a = b1v;
        g1a = __builtin_amdgcn_mfma_f32_16x16x32_f16(a1[0], bq0, g1a, 0, 0, 0);
        g1a = __builtin_amdgcn_mfma_f32_16x16x32_f16(a1[1], bq1, g1a, 0, 0, 0);
        f32x4 g1b = {0, 0, 0, 0};
        g1b = __builtin_amdgcn_mfma_f32_16x16x32_f16(a1[2], bq2, g1b, 0, 0, 0);
        g1b = __builtin_amdgcn_mfma_f32_16x16x32_f16(a1[3], bq3, g1b, 0, 0, 0);

        float g[4];
        #pragma unroll
        for (int r = 0; r < 4; ++r) {
            const float gs = hiH ? (g1a[r] + g1b[r]) : g0[r];
            g[r] = fmaf(wx[r], xv, gs);      // wx = 0 on hi lanes
        }

        // g[0]=-i, g[1]=-f, g[3]=-o (log2-folded); g[2]=-2*g~ (log2)
        const bool act = hiH ? doL1 : doL0;
        if (act) {
            float Ei = fexp2(g[0]);                  // e^{-i}
            float Ef = fexp2(g[1]);                  // e^{-f}
            float Eg = fexp2(-fabsf(g[2]));          // e^{-2|g~|}
            float Eo = fexp2(g[3]);                  // e^{-o}
            float it = copysignf((1.f - Eg) * frcp((1.f + Ei) * (1.f + Eg)), -g[2]);
            c = fmaf(frcp(1.f + Ef), c, it);
            float Ec = fexp2(-fabsf(K2 * c));        // e^{-2|c|}
            float h  = copysignf((1.f - Ec) * frcp((1.f + Eo) * (1.f + Ec)), c);
            if (wrOK) {
                if (last && hiH) {
                    sH2f[jj * NB + col] = h;        // h2(511) for the FC
                } else {
                    bw[wH] = (_Float16)h;           // single copy
                }
            }
        }
        __syncthreads();   // the ONLY barrier per step
    };

    body(0, sB[0], sB[1], true, false, false);
    #pragma unroll 1
    for (int i = 0; i < 255; ++i) {
        body(2 * i + 1, sB[1], sB[0], true, true, false);
        body(2 * i + 2, sB[0], sB[1], true, true, false);
    }
    body(511, sB[1], sB[0], true, true, false);
    body(512, sB[0], sB[1], false, true, true);

    // ---- FC epilogue: out[b] = fcW . h2_last[b] + fcb ----
    if (t < NB) {
        float sum = fcb[0];
        #pragma unroll
        for (int jx = 0; jx < H; ++jx) sum += fcW[jx] * sH2f[jx * NB + t];
        out[bbase + t] = sum;
    }
}

extern "C" void kernel_launch(void* const* d_in, const int* in_sizes, int n_in,
                              void* d_out, int out_size, void* d_ws, size_t ws_size,
                              hipStream_t stream)
{
    const float* x    = (const float*)d_in[0];
    const float* Wih0 = (const float*)d_in[1];
    const float* Whh0 = (const float*)d_in[2];
    const float* bih0 = (const float*)d_in[3];
    const float* bhh0 = (const float*)d_in[4];
    const float* Wih1 = (const float*)d_in[5];
    const float* Whh1 = (const float*)d_in[6];
    const float* bih1 = (const float*)d_in[7];
    const float* bhh1 = (const float*)d_in[8];
    const float* fcW  = (const float*)d_in[9];
    const float* fcb  = (const float*)d_in[10];

    lstm2_r16<<<BATCH / NB, NT, 0, stream>>>(
        x, Wih0, Whh0, bih0, bhh0, Wih1, Whh1, bih1, bhh1, fcW, fcb,
        (float*)d_out);
}